// Round 21
// baseline (58.845 us; speedup 1.0000x reference)
//
#include <hip/hip_runtime.h>

typedef short  bhalf8   __attribute__((ext_vector_type(8)));   // 8 bf16 (4 VGPRs)
typedef float  floatx16 __attribute__((ext_vector_type(16)));  // MFMA 32x32 acc
typedef float  float4e  __attribute__((ext_vector_type(4)));

#define NTOK 3136
#define CDIM 147
#define NQT  98    // 3136/32 q-tiles
#define KVT  49    // 3136/64 kv-tiles
#define NCHUNK 4
#define QTB8 13    // ceil(98/8) q-tile groups (8 waves/block)
#define NSPLITB (QTB8 * 8 * NCHUNK)  // 416 = 8 * 52 (clean XCD swizzle)
#define PARTB 4352 // bytes per partial: 2 regions x 2048 (bf16 O) + 256 (fp32 l)

static __device__ __forceinline__ unsigned short f2bf(float f) {
    unsigned u = __float_as_uint(f);
    u += 0x7fffu + ((u >> 16) & 1u);            // round-to-nearest-even
    return (unsigned short)(u >> 16);
}
static __device__ __forceinline__ float bf2f(unsigned short h) {
    return __uint_as_float(((unsigned)h) << 16);
}
// packed f32x2 -> bf16x2 via HW cvt (T12 recipe; no builtin on gfx950)
static __device__ __forceinline__ unsigned packbf2(float a, float b) {
    unsigned r;
    asm("v_cvt_pk_bf16_f32 %0, %1, %2" : "=v"(r) : "v"(a), "v"(b));
    return r;
}
static __device__ __forceinline__ float fexp2(float x) {
#if __has_builtin(__builtin_amdgcn_exp2f)
    return __builtin_amdgcn_exp2f(x);
#else
    return __expf(x * 0.69314718056f);
#endif
}

// ---------------------------------------------------------------------------
// Kernel 0: WbT[c][k] = bf16(W[k][c]), K padded 147->160. 192x160.
// ---------------------------------------------------------------------------
__global__ __launch_bounds__(256) void prep_w_kernel(
    const float* __restrict__ W, unsigned short* __restrict__ WbT)
{
    const int idx = blockIdx.x * 256 + threadIdx.x;
    if (idx >= 192 * 160) return;
    const int c = idx / 160, k = idx - c * 160;
    WbT[idx] = (k < CDIM) ? f2bf(W[(size_t)k * 192 + c]) : (unsigned short)0;
}

// ---------------------------------------------------------------------------
// Kernel 1: qkv via MFMA (q pre-scaled by SM = 0.125*log2e).
// ---------------------------------------------------------------------------
__global__ __launch_bounds__(384) void qkv_mfma_kernel(
    const float* __restrict__ x, const unsigned short* __restrict__ WbT,
    unsigned short* __restrict__ qb, unsigned short* __restrict__ kb,
    unsigned short* __restrict__ vT)
{
    __shared__ __align__(16) unsigned char xls[32 * 384];
    const int tid = threadIdx.x;
    const int wave = tid >> 6, lane = tid & 63;
    const int l31 = lane & 31, hi = lane >> 5;
    const int n0g = blockIdx.x * 32;
    const int b = n0g / NTOK, nn0 = n0g - b * NTOK;
    const float SM = 0.125f * 1.44269504f;      // scale * log2(e)

    for (int i = tid; i < 640; i += 384) {
        const int row = i / 20, c = i - row * 20;
        const float* src = x + (size_t)(n0g + row) * CDIM + c * 8;
        float f[8];
        if (c < 18) {
            const float4e a = *reinterpret_cast<const float4e*>(src);
            const float4e v2 = *reinterpret_cast<const float4e*>(src + 4);
            f[0]=a[0]; f[1]=a[1]; f[2]=a[2]; f[3]=a[3];
            f[4]=v2[0]; f[5]=v2[1]; f[6]=v2[2]; f[7]=v2[3];
        } else if (c == 18) {
            f[0]=src[0]; f[1]=src[1]; f[2]=src[2];
            f[3]=f[4]=f[5]=f[6]=f[7]=0.f;
        } else {
            f[0]=f[1]=f[2]=f[3]=f[4]=f[5]=f[6]=f[7]=0.f;
        }
        uint4 u;
        u.x = packbf2(f[0], f[1]); u.y = packbf2(f[2], f[3]);
        u.z = packbf2(f[4], f[5]); u.w = packbf2(f[6], f[7]);
        const int phys = (c & ~7) | ((c & 7) ^ (row & 7));
        *reinterpret_cast<uint4*>(&xls[row * 384 + phys * 16]) = u;
    }
    __syncthreads();

    const int wcol = wave * 32;                 // W col tile (q|k|v contiguous)
    const bhalf8* wrow = reinterpret_cast<const bhalf8*>(WbT + (size_t)(wcol + l31) * 160);
    floatx16 acc;
#pragma unroll
    for (int r = 0; r < 16; ++r) acc[r] = 0.f;

    if (wave < 4) {
#pragma unroll
        for (int s = 0; s < 10; ++s) {
            const int slot = 2 * s + hi;
            const int phys = (slot & ~7) | ((slot & 7) ^ (l31 & 7));
            const bhalf8 xf = *reinterpret_cast<const bhalf8*>(&xls[l31 * 384 + phys * 16]);
            acc = __builtin_amdgcn_mfma_f32_32x32x16_bf16(xf, wrow[slot], acc, 0, 0, 0);
        }
        unsigned short* dst = (wave < 2) ? qb : kb;
        const float scl = (wave < 2) ? SM : 1.0f;   // fold softmax scale into q
        const int c0 = (wave & 1) * 32 + l31;
#pragma unroll
        for (int r = 0; r < 16; ++r) {
            const int n = n0g + (r & 3) + 8 * (r >> 2) + 4 * hi;
            dst[(size_t)n * 64 + c0] = f2bf(acc[r] * scl);
        }
    } else {
#pragma unroll
        for (int s = 0; s < 10; ++s) {
            const int slot = 2 * s + hi;
            const int phys = (slot & ~7) | ((slot & 7) ^ (l31 & 7));
            const bhalf8 xf = *reinterpret_cast<const bhalf8*>(&xls[l31 * 384 + phys * 16]);
            acc = __builtin_amdgcn_mfma_f32_32x32x16_bf16(wrow[slot], xf, acc, 0, 0, 0);
        }
        const int nc = nn0 + l31;
#pragma unroll
        for (int r = 0; r < 16; ++r) {
            const int c = (wave - 4) * 32 + (r & 3) + 8 * (r >> 2) + 4 * hi;
            vT[((size_t)b * 64 + c) * NTOK + nc] = f2bf(acc[r]);
        }
    }
}

// ---------------------------------------------------------------------------
// Fragment builder (cvt_pk + lane32-swap expressed portably; round-0 note)
// ---------------------------------------------------------------------------
static __device__ __forceinline__ bhalf8 build_frag(unsigned a0, unsigned a1,
                                                    unsigned a2, unsigned a3, int hi)
{
    const unsigned py1 = __shfl_xor(hi ? a0 : a2, 32);
    const unsigned py2 = __shfl_xor(hi ? a1 : a3, 32);
    union { unsigned w[4]; bhalf8 v; } f;
    f.w[0] = hi ? py1 : a0;
    f.w[1] = hi ? py2 : a1;
    f.w[2] = hi ? a2 : py1;
    f.w[3] = hi ? a3 : py2;
    return f.v;
}

// Shared epilogue: out^T = W^T.(O/l) then +b +v, scattered fp32 stores
static __device__ __forceinline__ void attn_epilogue(
    const floatx16& accO0, const floatx16& accO1, float inv,
    const float* __restrict__ Wp, const float* __restrict__ bp,
    const unsigned short* __restrict__ vb, float* __restrict__ orow,
    int q, int l31, int hi)
{
    unsigned ok0[8], ok1[8];
#pragma unroll
    for (int w = 0; w < 8; ++w) {
        ok0[w] = packbf2(accO0[2 * w] * inv, accO0[2 * w + 1] * inv);
        ok1[w] = packbf2(accO1[2 * w] * inv, accO1[2 * w + 1] * inv);
    }
    floatx16 accP0, accP1;
#pragma unroll
    for (int r = 0; r < 16; ++r) { accP0[r] = 0.f; accP1[r] = 0.f; }
#pragma unroll
    for (int ks = 0; ks < 4; ++ks) {
        const int t = ks & 1;
        const bhalf8 of = (ks >> 1) ? build_frag(ok1[4*t], ok1[4*t+1], ok1[4*t+2], ok1[4*t+3], hi)
                                    : build_frag(ok0[4*t], ok0[4*t+1], ok0[4*t+2], ok0[4*t+3], hi);
        union { unsigned w[4]; bhalf8 v; } wa, wb;
#pragma unroll
        for (int jj = 0; jj < 4; ++jj) {
            const int d0 = 16 * ks + 8 * hi + 2 * jj;
            wa.w[jj] = packbf2(Wp[(size_t)d0 * 64 + l31],      Wp[(size_t)(d0 + 1) * 64 + l31]);
            wb.w[jj] = packbf2(Wp[(size_t)d0 * 64 + 32 + l31], Wp[(size_t)(d0 + 1) * 64 + 32 + l31]);
        }
        accP0 = __builtin_amdgcn_mfma_f32_32x32x16_bf16(wa.v, of, accP0, 0, 0, 0);
        accP1 = __builtin_amdgcn_mfma_f32_32x32x16_bf16(wb.v, of, accP1, 0, 0, 0);
    }
#pragma unroll
    for (int r = 0; r < 16; ++r) {
        const int e0 = (r & 3) + 8 * (r >> 2) + 4 * hi;
        const int e1 = e0 + 32;
        const float va = bf2f(vb[(size_t)e0 * NTOK + q]);
        const float vc = bf2f(vb[(size_t)e1 * NTOK + q]);
        orow[(size_t)q * 64 + e0] = accP0[r] + bp[e0] + va;
        orow[(size_t)q * 64 + e1] = accP1[r] + bp[e1] + vc;
    }
}

// ---------------------------------------------------------------------------
// Kernel 2a: LDS-staged split-K flash attention (no-max), bf16 partials.
// Round-16 structure + T1 XCD swizzle: 1-D grid of 416 blocks; bijective
// remap sw = (bid%8)*52 + bid/8 puts the 13 blocks sharing one (b,ck) K/V
// chunk on the same XCD (K/V staged from its L2, not 8x HBM copies).
// ---------------------------------------------------------------------------
__global__ __launch_bounds__(512) void attn_split_kernel(
    const unsigned short* __restrict__ qb,
    const unsigned short* __restrict__ kbf,
    const unsigned short* __restrict__ vT,
    char* __restrict__ part)
{
    __shared__ __align__(16) unsigned char lds[2][16384];  // [buf][K 8KB | V 8KB]
    const int tid  = threadIdx.x;
    const int wave = tid >> 6, lane = tid & 63;
    const int l31 = lane & 31, hi = lane >> 5;
    // XCD-aware bijective swizzle (416 = 8 * 52): same-(b,ck) groups colocate
    const int sw  = (blockIdx.x & 7) * (NSPLITB / 8) + (blockIdx.x >> 3);
    const int qtb = sw % QTB8;
    const int g   = sw / QTB8;            // 0..31
    const int b   = g & 7, ck = g >> 3;
    int qt = qtb * 8 + wave; if (qt >= NQT) qt = NQT - 1;   // dup work, benign
    const size_t bofs = (size_t)b * NTOK * 64;
    const int q0 = qt * 32;

    const bhalf8* qrow = reinterpret_cast<const bhalf8*>(qb + bofs + (size_t)(q0 + l31) * 64);
    bhalf8 Qf[4];
#pragma unroll
    for (int s = 0; s < 4; ++s) Qf[s] = qrow[2 * s + hi];

    floatx16 accO0, accO1, z16;
#pragma unroll
    for (int r = 0; r < 16; ++r) { accO0[r] = 0.f; accO1[r] = 0.f; z16[r] = 0.f; }
    float lsum = 0.f;

    const unsigned short* vb = vT + (size_t)b * 64 * NTOK;
    const int kv_lo = (ck * KVT) / NCHUNK;
    const int kv_hi = ((ck + 1) * KVT) / NCHUNK;

    // staging: 512 threads cover the 512 16B slots of K and of V
    const int r0 = tid >> 3,  s0i = tid & 7;       // row 0..63, slot 0..7
    const int swz0 = (s0i ^ (r0 & 7)) << 4;
    uint4 rK, rV;

#define STAGE_LOAD(kvt_) do {                                                   \
        rK = reinterpret_cast<const uint4*>(                                    \
            kbf + bofs + (size_t)(kvt_) * 64 * 64)[tid];                        \
        rV = *reinterpret_cast<const uint4*>(                                   \
            vb + (size_t)r0 * NTOK + (kvt_) * 64 + s0i * 8);                    \
    } while (0)

#define STAGE_WRITE(buf_) do {                                                  \
        *reinterpret_cast<uint4*>(&lds[buf_][r0 * 128 + swz0])        = rK;     \
        *reinterpret_cast<uint4*>(&lds[buf_][8192 + r0 * 128 + swz0]) = rV;     \
    } while (0)

    STAGE_LOAD(kv_lo);
    int buf = 0;
    const int kswz = (l31 & 7);
    for (int kvt = kv_lo; kvt < kv_hi; ++kvt) {
        STAGE_WRITE(buf);
        if (kvt + 1 < kv_hi) STAGE_LOAD(kvt + 1);  // prefetch under compute
        __syncthreads();

        // ---- QK^T from LDS (first k-step consumes persistent z16) ----
        floatx16 s0, s1;
        {
            const int sl = (hi ^ kswz) << 4;
            const bhalf8 kf0 = *reinterpret_cast<const bhalf8*>(&lds[buf][l31 * 128 + sl]);
            const bhalf8 kf1 = *reinterpret_cast<const bhalf8*>(&lds[buf][(32 + l31) * 128 + sl]);
            s0 = __builtin_amdgcn_mfma_f32_32x32x16_bf16(kf0, Qf[0], z16, 0, 0, 0);
            s1 = __builtin_amdgcn_mfma_f32_32x32x16_bf16(kf1, Qf[0], z16, 0, 0, 0);
        }
#pragma unroll
        for (int s = 1; s < 4; ++s) {
            const int sl = ((2 * s + hi) ^ kswz) << 4;
            const bhalf8 kf0 = *reinterpret_cast<const bhalf8*>(&lds[buf][l31 * 128 + sl]);
            const bhalf8 kf1 = *reinterpret_cast<const bhalf8*>(&lds[buf][(32 + l31) * 128 + sl]);
            s0 = __builtin_amdgcn_mfma_f32_32x32x16_bf16(kf0, Qf[s], s0, 0, 0, 0);
            s1 = __builtin_amdgcn_mfma_f32_32x32x16_bf16(kf1, Qf[s], s1, 0, 0, 0);
        }
        // ---- no-max softmax (scale pre-folded into q) ----
        float ps0 = 0.f, ps1 = 0.f;
#pragma unroll
        for (int r = 0; r < 16; ++r) {
            const float p0 = fexp2(s0[r]); s0[r] = p0;
            const float p1 = fexp2(s1[r]); s1[r] = p1;
            ps0 += p0; ps1 += p1;
        }
        lsum += ps0 + ps1;
        unsigned pk0[8], pk1[8];
#pragma unroll
        for (int w = 0; w < 8; ++w) {
            pk0[w] = packbf2(s0[2 * w], s0[2 * w + 1]);
            pk1[w] = packbf2(s1[2 * w], s1[2 * w + 1]);
        }
        // ---- PV from LDS ----
#pragma unroll
        for (int u = 0; u < 2; ++u) {
#pragma unroll
            for (int t = 0; t < 2; ++t) {
                const bhalf8 pf = u ? build_frag(pk1[4*t], pk1[4*t+1], pk1[4*t+2], pk1[4*t+3], hi)
                                    : build_frag(pk0[4*t], pk0[4*t+1], pk0[4*t+2], pk0[4*t+3], hi);
                const int sl = ((4 * u + 2 * t + hi) ^ kswz) << 4;
                const bhalf8 v0 = *reinterpret_cast<const bhalf8*>(&lds[buf][8192 + l31 * 128 + sl]);
                const bhalf8 v1 = *reinterpret_cast<const bhalf8*>(&lds[buf][8192 + (32 + l31) * 128 + sl]);
                accO0 = __builtin_amdgcn_mfma_f32_32x32x16_bf16(v0, pf, accO0, 0, 0, 0);
                accO1 = __builtin_amdgcn_mfma_f32_32x32x16_bf16(v1, pf, accO1, 0, 0, 0);
            }
        }
        buf ^= 1;
    }
#undef STAGE_LOAD
#undef STAGE_WRITE

    char* pbb = part + ((size_t)(b * NQT + qt) * NCHUNK + ck) * PARTB;
#pragma unroll
    for (int rg = 0; rg < 4; ++rg) {
        uint2 w0, w1;
        w0.x = packbf2(accO0[4*rg],     accO0[4*rg + 1]);
        w0.y = packbf2(accO0[4*rg + 2], accO0[4*rg + 3]);
        w1.x = packbf2(accO1[4*rg],     accO1[4*rg + 1]);
        w1.y = packbf2(accO1[4*rg + 2], accO1[4*rg + 3]);
        *reinterpret_cast<uint2*>(pbb + (rg * 64 + lane) * 8)        = w0;
        *reinterpret_cast<uint2*>(pbb + 2048 + (rg * 64 + lane) * 8) = w1;
    }
    *reinterpret_cast<float*>(pbb + 4096 + lane * 4) = lsum;
}

// ---------------------------------------------------------------------------
// Kernel 2b: combine bf16 partials (plain sum) + out-proj + bias + v.
// ---------------------------------------------------------------------------
__global__ __launch_bounds__(256) void attn_combine_kernel(
    const char* __restrict__ part,
    const unsigned short* __restrict__ vT,
    const float* __restrict__ Wp, const float* __restrict__ bp,
    float* __restrict__ out)
{
    const int wid  = blockIdx.x * 4 + (threadIdx.x >> 6);
    const int lane = threadIdx.x & 63;
    const int qt   = wid % NQT;
    const int b    = wid / NQT;
    const int l31 = lane & 31, hi = lane >> 5;
    const char* pbase = part + (size_t)(b * NQT + qt) * NCHUNK * PARTB;

    floatx16 accO0, accO1;
#pragma unroll
    for (int r = 0; r < 16; ++r) { accO0[r] = 0.f; accO1[r] = 0.f; }
    float lsum = 0.f;
#pragma unroll
    for (int c = 0; c < NCHUNK; ++c) {
        const char* pbb = pbase + (size_t)c * PARTB;
#pragma unroll
        for (int rg = 0; rg < 4; ++rg) {
            const uint2 u0 = *reinterpret_cast<const uint2*>(pbb + (rg * 64 + lane) * 8);
            const uint2 u1 = *reinterpret_cast<const uint2*>(pbb + 2048 + (rg * 64 + lane) * 8);
            accO0[4*rg]     += __uint_as_float(u0.x << 16);
            accO0[4*rg + 1] += __uint_as_float(u0.x & 0xffff0000u);
            accO0[4*rg + 2] += __uint_as_float(u0.y << 16);
            accO0[4*rg + 3] += __uint_as_float(u0.y & 0xffff0000u);
            accO1[4*rg]     += __uint_as_float(u1.x << 16);
            accO1[4*rg + 1] += __uint_as_float(u1.x & 0xffff0000u);
            accO1[4*rg + 2] += __uint_as_float(u1.y << 16);
            accO1[4*rg + 3] += __uint_as_float(u1.y & 0xffff0000u);
        }
        lsum += *reinterpret_cast<const float*>(pbb + 4096 + lane * 4);
    }
    const float L = lsum + __shfl_xor(lsum, 32);
    const unsigned short* vb = vT + (size_t)b * 64 * NTOK;
    attn_epilogue(accO0, accO1, 1.0f / L, Wp, bp, vb, out + (size_t)b * NTOK * 64,
                  qt * 32 + l31, l31, hi);
}

// ---------------------------------------------------------------------------
// Fallback: monolithic attention, global K/V reads (only if ws too small)
// ---------------------------------------------------------------------------
__global__ __launch_bounds__(64) void attn_kernel(
    const unsigned short* __restrict__ qb,
    const unsigned short* __restrict__ kbf,
    const unsigned short* __restrict__ vT,
    const float* __restrict__ Wp, const float* __restrict__ bp,
    float* __restrict__ out)
{
    const int qt = blockIdx.x, b = blockIdx.y;
    const int lane = threadIdx.x;
    const int l31 = lane & 31, hi = lane >> 5;
    const size_t bofs = (size_t)b * NTOK * 64;
    const int q0 = qt * 32;

    const bhalf8* qrow = reinterpret_cast<const bhalf8*>(qb + bofs + (size_t)(q0 + l31) * 64);
    bhalf8 Qf[4];
#pragma unroll
    for (int s = 0; s < 4; ++s) Qf[s] = qrow[2 * s + hi];

    floatx16 accO0, accO1;
#pragma unroll
    for (int r = 0; r < 16; ++r) { accO0[r] = 0.f; accO1[r] = 0.f; }
    float lsum = 0.f;
    const unsigned short* vb = vT + (size_t)b * 64 * NTOK;
    for (int kvt = 0; kvt < KVT; ++kvt) {
        const int kv0 = kvt * 64;
        const bhalf8* kr0 = reinterpret_cast<const bhalf8*>(kbf + bofs + (size_t)(kv0 + l31) * 64);
        const bhalf8* kr1 = reinterpret_cast<const bhalf8*>(kbf + bofs + (size_t)(kv0 + 32 + l31) * 64);
        floatx16 s0, s1;
#pragma unroll
        for (int r = 0; r < 16; ++r) { s0[r] = 0.f; s1[r] = 0.f; }
#pragma unroll
        for (int s = 0; s < 4; ++s) {
            s0 = __builtin_amdgcn_mfma_f32_32x32x16_bf16(kr0[2 * s + hi], Qf[s], s0, 0, 0, 0);
            s1 = __builtin_amdgcn_mfma_f32_32x32x16_bf16(kr1[2 * s + hi], Qf[s], s1, 0, 0, 0);
        }
        float ps0 = 0.f, ps1 = 0.f;
#pragma unroll
        for (int r = 0; r < 16; ++r) {
            const float p0 = fexp2(s0[r]); s0[r] = p0;
            const float p1 = fexp2(s1[r]); s1[r] = p1;
            ps0 += p0; ps1 += p1;
        }
        lsum += ps0 + ps1;
        unsigned pk0[8], pk1[8];
#pragma unroll
        for (int w = 0; w < 8; ++w) {
            pk0[w] = packbf2(s0[2 * w], s0[2 * w + 1]);
            pk1[w] = packbf2(s1[2 * w], s1[2 * w + 1]);
        }
#pragma unroll
        for (int u = 0; u < 2; ++u) {
#pragma unroll
            for (int t = 0; t < 2; ++t) {
                const bhalf8 pf = u ? build_frag(pk1[4*t], pk1[4*t+1], pk1[4*t+2], pk1[4*t+3], hi)
                                    : build_frag(pk0[4*t], pk0[4*t+1], pk0[4*t+2], pk0[4*t+3], hi);
                const int col = kv0 + 32 * u + 16 * t + 8 * hi;
                const bhalf8 v0 = *reinterpret_cast<const bhalf8*>(vb + (size_t)l31 * NTOK + col);
                const bhalf8 v1 = *reinterpret_cast<const bhalf8*>(vb + (size_t)(32 + l31) * NTOK + col);
                accO0 = __builtin_amdgcn_mfma_f32_32x32x16_bf16(v0, pf, accO0, 0, 0, 0);
                accO1 = __builtin_amdgcn_mfma_f32_32x32x16_bf16(v1, pf, accO1, 0, 0, 0);
            }
        }
    }
    const float L = lsum + __shfl_xor(lsum, 32);
    attn_epilogue(accO0, accO1, 1.0f / L, Wp, bp, vb, out + bofs,
                  q0 + l31, l31, hi);
}

extern "C" void kernel_launch(void* const* d_in, const int* in_sizes, int n_in,
                              void* d_out, int out_size, void* d_ws, size_t ws_size,
                              hipStream_t stream)
{
    const float* x  = (const float*)d_in[0];
    const float* Wq = (const float*)d_in[1];
    const float* Wp = (const float*)d_in[2];
    const float* bp = (const float*)d_in[3];
    float* out = (float*)d_out;

    unsigned short* qbuf = (unsigned short*)d_ws;                 // 3x 8*3136*64 bf16
    unsigned short* kbuf = qbuf + (size_t)8 * NTOK * 64;
    unsigned short* vTb  = kbuf + (size_t)8 * NTOK * 64;
    const size_t bf_bytes = (size_t)3 * 8 * NTOK * 64 * 2;        // 9.63 MB
    char* part = (char*)d_ws + bf_bytes;
    const size_t part_bytes = (size_t)8 * NQT * NCHUNK * PARTB;   // 13.6 MB
    unsigned short* WbT = (unsigned short*)((char*)d_ws + bf_bytes + part_bytes);
    const size_t need = bf_bytes + part_bytes + 192 * 160 * 2;    // ~23 MB

    if (ws_size >= need) {
        prep_w_kernel<<<dim3(120), 256, 0, stream>>>(Wq, WbT);
        qkv_mfma_kernel<<<dim3(8 * NTOK / 32), 384, 0, stream>>>(x, WbT, qbuf, kbuf, vTb);
        attn_split_kernel<<<dim3(NSPLITB), 512, 0, stream>>>(qbuf, kbuf, vTb, part);
        attn_combine_kernel<<<dim3(8 * NQT / 4), 256, 0, stream>>>(part, vTb, Wp, bp, out);
    } else {
        prep_w_kernel<<<dim3(120), 256, 0, stream>>>(Wq, (unsigned short*)part);
        qkv_mfma_kernel<<<dim3(8 * NTOK / 32), 384, 0, stream>>>(x, (unsigned short*)part, qbuf, kbuf, vTb);
        attn_kernel<<<dim3(NQT, 8), 64, 0, stream>>>(qbuf, kbuf, vTb, Wp, bp, out);
    }
}

// Round 22
// 57.591 us; speedup vs baseline: 1.0218x; 1.0218x over previous
//
#include <hip/hip_runtime.h>

typedef short  bhalf8   __attribute__((ext_vector_type(8)));   // 8 bf16 (4 VGPRs)
typedef float  floatx16 __attribute__((ext_vector_type(16)));  // MFMA 32x32 acc
typedef float  float4e  __attribute__((ext_vector_type(4)));

#define NTOK 3136
#define CDIM 147
#define NQT  98    // 3136/32 q-tiles
#define KVT  49    // 3136/64 kv-tiles
#define NCHUNK 4
#define QTB8 13    // ceil(98/8) q-tile groups (8 waves/block)
#define PARTB 4352 // bytes per partial: 2 regions x 2048 (bf16 O) + 256 (fp32 l)

static __device__ __forceinline__ unsigned short f2bf(float f) {
    unsigned u = __float_as_uint(f);
    u += 0x7fffu + ((u >> 16) & 1u);            // round-to-nearest-even
    return (unsigned short)(u >> 16);
}
static __device__ __forceinline__ float bf2f(unsigned short h) {
    return __uint_as_float(((unsigned)h) << 16);
}
// packed f32x2 -> bf16x2 via HW cvt (T12 recipe; no builtin on gfx950)
static __device__ __forceinline__ unsigned packbf2(float a, float b) {
    unsigned r;
    asm("v_cvt_pk_bf16_f32 %0, %1, %2" : "=v"(r) : "v"(a), "v"(b));
    return r;
}
static __device__ __forceinline__ float fexp2(float x) {
#if __has_builtin(__builtin_amdgcn_exp2f)
    return __builtin_amdgcn_exp2f(x);
#else
    return __expf(x * 0.69314718056f);
#endif
}

// ---------------------------------------------------------------------------
// Kernel 0: WbT[c][k] = bf16(W[k][c]), K padded 147->160. 192x160.
// ---------------------------------------------------------------------------
__global__ __launch_bounds__(256) void prep_w_kernel(
    const float* __restrict__ W, unsigned short* __restrict__ WbT)
{
    const int idx = blockIdx.x * 256 + threadIdx.x;
    if (idx >= 192 * 160) return;
    const int c = idx / 160, k = idx - c * 160;
    WbT[idx] = (k < CDIM) ? f2bf(W[(size_t)k * 192 + c]) : (unsigned short)0;
}

// ---------------------------------------------------------------------------
// Kernel 1: qkv via MFMA (q pre-scaled by SM = 0.125*log2e).
// ---------------------------------------------------------------------------
__global__ __launch_bounds__(384) void qkv_mfma_kernel(
    const float* __restrict__ x, const unsigned short* __restrict__ WbT,
    unsigned short* __restrict__ qb, unsigned short* __restrict__ kb,
    unsigned short* __restrict__ vT)
{
    __shared__ __align__(16) unsigned char xls[32 * 384];
    const int tid = threadIdx.x;
    const int wave = tid >> 6, lane = tid & 63;
    const int l31 = lane & 31, hi = lane >> 5;
    const int n0g = blockIdx.x * 32;
    const int b = n0g / NTOK, nn0 = n0g - b * NTOK;
    const float SM = 0.125f * 1.44269504f;      // scale * log2(e)

    for (int i = tid; i < 640; i += 384) {
        const int row = i / 20, c = i - row * 20;
        const float* src = x + (size_t)(n0g + row) * CDIM + c * 8;
        float f[8];
        if (c < 18) {
            const float4e a = *reinterpret_cast<const float4e*>(src);
            const float4e v2 = *reinterpret_cast<const float4e*>(src + 4);
            f[0]=a[0]; f[1]=a[1]; f[2]=a[2]; f[3]=a[3];
            f[4]=v2[0]; f[5]=v2[1]; f[6]=v2[2]; f[7]=v2[3];
        } else if (c == 18) {
            f[0]=src[0]; f[1]=src[1]; f[2]=src[2];
            f[3]=f[4]=f[5]=f[6]=f[7]=0.f;
        } else {
            f[0]=f[1]=f[2]=f[3]=f[4]=f[5]=f[6]=f[7]=0.f;
        }
        uint4 u;
        u.x = packbf2(f[0], f[1]); u.y = packbf2(f[2], f[3]);
        u.z = packbf2(f[4], f[5]); u.w = packbf2(f[6], f[7]);
        const int phys = (c & ~7) | ((c & 7) ^ (row & 7));
        *reinterpret_cast<uint4*>(&xls[row * 384 + phys * 16]) = u;
    }
    __syncthreads();

    const int wcol = wave * 32;                 // W col tile (q|k|v contiguous)
    const bhalf8* wrow = reinterpret_cast<const bhalf8*>(WbT + (size_t)(wcol + l31) * 160);
    floatx16 acc;
#pragma unroll
    for (int r = 0; r < 16; ++r) acc[r] = 0.f;

    if (wave < 4) {
#pragma unroll
        for (int s = 0; s < 10; ++s) {
            const int slot = 2 * s + hi;
            const int phys = (slot & ~7) | ((slot & 7) ^ (l31 & 7));
            const bhalf8 xf = *reinterpret_cast<const bhalf8*>(&xls[l31 * 384 + phys * 16]);
            acc = __builtin_amdgcn_mfma_f32_32x32x16_bf16(xf, wrow[slot], acc, 0, 0, 0);
        }
        unsigned short* dst = (wave < 2) ? qb : kb;
        const float scl = (wave < 2) ? SM : 1.0f;   // fold softmax scale into q
        const int c0 = (wave & 1) * 32 + l31;
#pragma unroll
        for (int r = 0; r < 16; ++r) {
            const int n = n0g + (r & 3) + 8 * (r >> 2) + 4 * hi;
            dst[(size_t)n * 64 + c0] = f2bf(acc[r] * scl);
        }
    } else {
#pragma unroll
        for (int s = 0; s < 10; ++s) {
            const int slot = 2 * s + hi;
            const int phys = (slot & ~7) | ((slot & 7) ^ (l31 & 7));
            const bhalf8 xf = *reinterpret_cast<const bhalf8*>(&xls[l31 * 384 + phys * 16]);
            acc = __builtin_amdgcn_mfma_f32_32x32x16_bf16(wrow[slot], xf, acc, 0, 0, 0);
        }
        const int nc = nn0 + l31;
#pragma unroll
        for (int r = 0; r < 16; ++r) {
            const int c = (wave - 4) * 32 + (r & 3) + 8 * (r >> 2) + 4 * hi;
            vT[((size_t)b * 64 + c) * NTOK + nc] = f2bf(acc[r]);
        }
    }
}

// ---------------------------------------------------------------------------
// Fragment builder (cvt_pk + lane32-swap expressed portably; round-0 note)
// ---------------------------------------------------------------------------
static __device__ __forceinline__ bhalf8 build_frag(unsigned a0, unsigned a1,
                                                    unsigned a2, unsigned a3, int hi)
{
    const unsigned py1 = __shfl_xor(hi ? a0 : a2, 32);
    const unsigned py2 = __shfl_xor(hi ? a1 : a3, 32);
    union { unsigned w[4]; bhalf8 v; } f;
    f.w[0] = hi ? py1 : a0;
    f.w[1] = hi ? py2 : a1;
    f.w[2] = hi ? a2 : py1;
    f.w[3] = hi ? a3 : py2;
    return f.v;
}

// Shared epilogue: out^T = W^T.(O/l) then +b +v, scattered fp32 stores
static __device__ __forceinline__ void attn_epilogue(
    const floatx16& accO0, const floatx16& accO1, float inv,
    const float* __restrict__ Wp, const float* __restrict__ bp,
    const unsigned short* __restrict__ vb, float* __restrict__ orow,
    int q, int l31, int hi)
{
    unsigned ok0[8], ok1[8];
#pragma unroll
    for (int w = 0; w < 8; ++w) {
        ok0[w] = packbf2(accO0[2 * w] * inv, accO0[2 * w + 1] * inv);
        ok1[w] = packbf2(accO1[2 * w] * inv, accO1[2 * w + 1] * inv);
    }
    floatx16 accP0, accP1;
#pragma unroll
    for (int r = 0; r < 16; ++r) { accP0[r] = 0.f; accP1[r] = 0.f; }
#pragma unroll
    for (int ks = 0; ks < 4; ++ks) {
        const int t = ks & 1;
        const bhalf8 of = (ks >> 1) ? build_frag(ok1[4*t], ok1[4*t+1], ok1[4*t+2], ok1[4*t+3], hi)
                                    : build_frag(ok0[4*t], ok0[4*t+1], ok0[4*t+2], ok0[4*t+3], hi);
        union { unsigned w[4]; bhalf8 v; } wa, wb;
#pragma unroll
        for (int jj = 0; jj < 4; ++jj) {
            const int d0 = 16 * ks + 8 * hi + 2 * jj;
            wa.w[jj] = packbf2(Wp[(size_t)d0 * 64 + l31],      Wp[(size_t)(d0 + 1) * 64 + l31]);
            wb.w[jj] = packbf2(Wp[(size_t)d0 * 64 + 32 + l31], Wp[(size_t)(d0 + 1) * 64 + 32 + l31]);
        }
        accP0 = __builtin_amdgcn_mfma_f32_32x32x16_bf16(wa.v, of, accP0, 0, 0, 0);
        accP1 = __builtin_amdgcn_mfma_f32_32x32x16_bf16(wb.v, of, accP1, 0, 0, 0);
    }
#pragma unroll
    for (int r = 0; r < 16; ++r) {
        const int e0 = (r & 3) + 8 * (r >> 2) + 4 * hi;
        const int e1 = e0 + 32;
        const float va = bf2f(vb[(size_t)e0 * NTOK + q]);
        const float vc = bf2f(vb[(size_t)e1 * NTOK + q]);
        orow[(size_t)q * 64 + e0] = accP0[r] + bp[e0] + va;
        orow[(size_t)q * 64 + e1] = accP1[r] + bp[e1] + vc;
    }
}

// ---------------------------------------------------------------------------
// Kernel 2a: LDS-staged split-K flash attention (no-max), bf16 partials.
// Best-known config: 8 waves / 8 q-tiles share one K/V stage, 32KB
// double-buffer, 1 barrier/tile, plain stores, NCHUNK=4, separate combine.
// ---------------------------------------------------------------------------
__global__ __launch_bounds__(512) void attn_split_kernel(
    const unsigned short* __restrict__ qb,
    const unsigned short* __restrict__ kbf,
    const unsigned short* __restrict__ vT,
    char* __restrict__ part)
{
    __shared__ __align__(16) unsigned char lds[2][16384];  // [buf][K 8KB | V 8KB]
    const int tid  = threadIdx.x;
    const int wave = tid >> 6, lane = tid & 63;
    const int l31 = lane & 31, hi = lane >> 5;
    const int qtb = blockIdx.x, b = blockIdx.y, ck = blockIdx.z;
    int qt = qtb * 8 + wave; if (qt >= NQT) qt = NQT - 1;   // dup work, benign
    const size_t bofs = (size_t)b * NTOK * 64;
    const int q0 = qt * 32;

    const bhalf8* qrow = reinterpret_cast<const bhalf8*>(qb + bofs + (size_t)(q0 + l31) * 64);
    bhalf8 Qf[4];
#pragma unroll
    for (int s = 0; s < 4; ++s) Qf[s] = qrow[2 * s + hi];

    floatx16 accO0, accO1, z16;
#pragma unroll
    for (int r = 0; r < 16; ++r) { accO0[r] = 0.f; accO1[r] = 0.f; z16[r] = 0.f; }
    float lsum = 0.f;

    const unsigned short* vb = vT + (size_t)b * 64 * NTOK;
    const int kv_lo = (ck * KVT) / NCHUNK;
    const int kv_hi = ((ck + 1) * KVT) / NCHUNK;

    // staging: 512 threads cover the 512 16B slots of K and of V
    const int r0 = tid >> 3,  s0i = tid & 7;       // row 0..63, slot 0..7
    const int swz0 = (s0i ^ (r0 & 7)) << 4;
    uint4 rK, rV;

#define STAGE_LOAD(kvt_) do {                                                   \
        rK = reinterpret_cast<const uint4*>(                                    \
            kbf + bofs + (size_t)(kvt_) * 64 * 64)[tid];                        \
        rV = *reinterpret_cast<const uint4*>(                                   \
            vb + (size_t)r0 * NTOK + (kvt_) * 64 + s0i * 8);                    \
    } while (0)

#define STAGE_WRITE(buf_) do {                                                  \
        *reinterpret_cast<uint4*>(&lds[buf_][r0 * 128 + swz0])        = rK;     \
        *reinterpret_cast<uint4*>(&lds[buf_][8192 + r0 * 128 + swz0]) = rV;     \
    } while (0)

    STAGE_LOAD(kv_lo);
    int buf = 0;
    const int kswz = (l31 & 7);
    for (int kvt = kv_lo; kvt < kv_hi; ++kvt) {
        STAGE_WRITE(buf);
        if (kvt + 1 < kv_hi) STAGE_LOAD(kvt + 1);  // prefetch under compute
        __syncthreads();

        // ---- QK^T from LDS (first k-step consumes persistent z16) ----
        floatx16 s0, s1;
        {
            const int sl = (hi ^ kswz) << 4;
            const bhalf8 kf0 = *reinterpret_cast<const bhalf8*>(&lds[buf][l31 * 128 + sl]);
            const bhalf8 kf1 = *reinterpret_cast<const bhalf8*>(&lds[buf][(32 + l31) * 128 + sl]);
            s0 = __builtin_amdgcn_mfma_f32_32x32x16_bf16(kf0, Qf[0], z16, 0, 0, 0);
            s1 = __builtin_amdgcn_mfma_f32_32x32x16_bf16(kf1, Qf[0], z16, 0, 0, 0);
        }
#pragma unroll
        for (int s = 1; s < 4; ++s) {
            const int sl = ((2 * s + hi) ^ kswz) << 4;
            const bhalf8 kf0 = *reinterpret_cast<const bhalf8*>(&lds[buf][l31 * 128 + sl]);
            const bhalf8 kf1 = *reinterpret_cast<const bhalf8*>(&lds[buf][(32 + l31) * 128 + sl]);
            s0 = __builtin_amdgcn_mfma_f32_32x32x16_bf16(kf0, Qf[s], s0, 0, 0, 0);
            s1 = __builtin_amdgcn_mfma_f32_32x32x16_bf16(kf1, Qf[s], s1, 0, 0, 0);
        }
        // ---- no-max softmax (scale pre-folded into q) ----
        float ps0 = 0.f, ps1 = 0.f;
#pragma unroll
        for (int r = 0; r < 16; ++r) {
            const float p0 = fexp2(s0[r]); s0[r] = p0;
            const float p1 = fexp2(s1[r]); s1[r] = p1;
            ps0 += p0; ps1 += p1;
        }
        lsum += ps0 + ps1;
        unsigned pk0[8], pk1[8];
#pragma unroll
        for (int w = 0; w < 8; ++w) {
            pk0[w] = packbf2(s0[2 * w], s0[2 * w + 1]);
            pk1[w] = packbf2(s1[2 * w], s1[2 * w + 1]);
        }
        // ---- PV from LDS ----
#pragma unroll
        for (int u = 0; u < 2; ++u) {
#pragma unroll
            for (int t = 0; t < 2; ++t) {
                const bhalf8 pf = u ? build_frag(pk1[4*t], pk1[4*t+1], pk1[4*t+2], pk1[4*t+3], hi)
                                    : build_frag(pk0[4*t], pk0[4*t+1], pk0[4*t+2], pk0[4*t+3], hi);
                const int sl = ((4 * u + 2 * t + hi) ^ kswz) << 4;
                const bhalf8 v0 = *reinterpret_cast<const bhalf8*>(&lds[buf][8192 + l31 * 128 + sl]);
                const bhalf8 v1 = *reinterpret_cast<const bhalf8*>(&lds[buf][8192 + (32 + l31) * 128 + sl]);
                accO0 = __builtin_amdgcn_mfma_f32_32x32x16_bf16(v0, pf, accO0, 0, 0, 0);
                accO1 = __builtin_amdgcn_mfma_f32_32x32x16_bf16(v1, pf, accO1, 0, 0, 0);
            }
        }
        buf ^= 1;
    }
#undef STAGE_LOAD
#undef STAGE_WRITE

    char* pbb = part + ((size_t)(b * NQT + qt) * NCHUNK + ck) * PARTB;
#pragma unroll
    for (int rg = 0; rg < 4; ++rg) {
        uint2 w0, w1;
        w0.x = packbf2(accO0[4*rg],     accO0[4*rg + 1]);
        w0.y = packbf2(accO0[4*rg + 2], accO0[4*rg + 3]);
        w1.x = packbf2(accO1[4*rg],     accO1[4*rg + 1]);
        w1.y = packbf2(accO1[4*rg + 2], accO1[4*rg + 3]);
        *reinterpret_cast<uint2*>(pbb + (rg * 64 + lane) * 8)        = w0;
        *reinterpret_cast<uint2*>(pbb + 2048 + (rg * 64 + lane) * 8) = w1;
    }
    *reinterpret_cast<float*>(pbb + 4096 + lane * 4) = lsum;
}

// ---------------------------------------------------------------------------
// Kernel 2b: combine bf16 partials (plain sum) + out-proj + bias + v.
// ---------------------------------------------------------------------------
__global__ __launch_bounds__(256) void attn_combine_kernel(
    const char* __restrict__ part,
    const unsigned short* __restrict__ vT,
    const float* __restrict__ Wp, const float* __restrict__ bp,
    float* __restrict__ out)
{
    const int wid  = blockIdx.x * 4 + (threadIdx.x >> 6);
    const int lane = threadIdx.x & 63;
    const int qt   = wid % NQT;
    const int b    = wid / NQT;
    const int l31 = lane & 31, hi = lane >> 5;
    const char* pbase = part + (size_t)(b * NQT + qt) * NCHUNK * PARTB;

    floatx16 accO0, accO1;
#pragma unroll
    for (int r = 0; r < 16; ++r) { accO0[r] = 0.f; accO1[r] = 0.f; }
    float lsum = 0.f;
#pragma unroll
    for (int c = 0; c < NCHUNK; ++c) {
        const char* pbb = pbase + (size_t)c * PARTB;
#pragma unroll
        for (int rg = 0; rg < 4; ++rg) {
            const uint2 u0 = *reinterpret_cast<const uint2*>(pbb + (rg * 64 + lane) * 8);
            const uint2 u1 = *reinterpret_cast<const uint2*>(pbb + 2048 + (rg * 64 + lane) * 8);
            accO0[4*rg]     += __uint_as_float(u0.x << 16);
            accO0[4*rg + 1] += __uint_as_float(u0.x & 0xffff0000u);
            accO0[4*rg + 2] += __uint_as_float(u0.y << 16);
            accO0[4*rg + 3] += __uint_as_float(u0.y & 0xffff0000u);
            accO1[4*rg]     += __uint_as_float(u1.x << 16);
            accO1[4*rg + 1] += __uint_as_float(u1.x & 0xffff0000u);
            accO1[4*rg + 2] += __uint_as_float(u1.y << 16);
            accO1[4*rg + 3] += __uint_as_float(u1.y & 0xffff0000u);
        }
        lsum += *reinterpret_cast<const float*>(pbb + 4096 + lane * 4);
    }
    const float L = lsum + __shfl_xor(lsum, 32);
    const unsigned short* vb = vT + (size_t)b * 64 * NTOK;
    attn_epilogue(accO0, accO1, 1.0f / L, Wp, bp, vb, out + (size_t)b * NTOK * 64,
                  qt * 32 + l31, l31, hi);
}

// ---------------------------------------------------------------------------
// Fallback: monolithic attention, global K/V reads (only if ws too small)
// ---------------------------------------------------------------------------
__global__ __launch_bounds__(64) void attn_kernel(
    const unsigned short* __restrict__ qb,
    const unsigned short* __restrict__ kbf,
    const unsigned short* __restrict__ vT,
    const float* __restrict__ Wp, const float* __restrict__ bp,
    float* __restrict__ out)
{
    const int qt = blockIdx.x, b = blockIdx.y;
    const int lane = threadIdx.x;
    const int l31 = lane & 31, hi = lane >> 5;
    const size_t bofs = (size_t)b * NTOK * 64;
    const int q0 = qt * 32;

    const bhalf8* qrow = reinterpret_cast<const bhalf8*>(qb + bofs + (size_t)(q0 + l31) * 64);
    bhalf8 Qf[4];
#pragma unroll
    for (int s = 0; s < 4; ++s) Qf[s] = qrow[2 * s + hi];

    floatx16 accO0, accO1;
#pragma unroll
    for (int r = 0; r < 16; ++r) { accO0[r] = 0.f; accO1[r] = 0.f; }
    float lsum = 0.f;
    const unsigned short* vb = vT + (size_t)b * 64 * NTOK;
    for (int kvt = 0; kvt < KVT; ++kvt) {
        const int kv0 = kvt * 64;
        const bhalf8* kr0 = reinterpret_cast<const bhalf8*>(kbf + bofs + (size_t)(kv0 + l31) * 64);
        const bhalf8* kr1 = reinterpret_cast<const bhalf8*>(kbf + bofs + (size_t)(kv0 + 32 + l31) * 64);
        floatx16 s0, s1;
#pragma unroll
        for (int r = 0; r < 16; ++r) { s0[r] = 0.f; s1[r] = 0.f; }
#pragma unroll
        for (int s = 0; s < 4; ++s) {
            s0 = __builtin_amdgcn_mfma_f32_32x32x16_bf16(kr0[2 * s + hi], Qf[s], s0, 0, 0, 0);
            s1 = __builtin_amdgcn_mfma_f32_32x32x16_bf16(kr1[2 * s + hi], Qf[s], s1, 0, 0, 0);
        }
        float ps0 = 0.f, ps1 = 0.f;
#pragma unroll
        for (int r = 0; r < 16; ++r) {
            const float p0 = fexp2(s0[r]); s0[r] = p0;
            const float p1 = fexp2(s1[r]); s1[r] = p1;
            ps0 += p0; ps1 += p1;
        }
        lsum += ps0 + ps1;
        unsigned pk0[8], pk1[8];
#pragma unroll
        for (int w = 0; w < 8; ++w) {
            pk0[w] = packbf2(s0[2 * w], s0[2 * w + 1]);
            pk1[w] = packbf2(s1[2 * w], s1[2 * w + 1]);
        }
#pragma unroll
        for (int u = 0; u < 2; ++u) {
#pragma unroll
            for (int t = 0; t < 2; ++t) {
                const bhalf8 pf = u ? build_frag(pk1[4*t], pk1[4*t+1], pk1[4*t+2], pk1[4*t+3], hi)
                                    : build_frag(pk0[4*t], pk0[4*t+1], pk0[4*t+2], pk0[4*t+3], hi);
                const int col = kv0 + 32 * u + 16 * t + 8 * hi;
                const bhalf8 v0 = *reinterpret_cast<const bhalf8*>(vb + (size_t)l31 * NTOK + col);
                const bhalf8 v1 = *reinterpret_cast<const bhalf8*>(vb + (size_t)(32 + l31) * NTOK + col);
                accO0 = __builtin_amdgcn_mfma_f32_32x32x16_bf16(v0, pf, accO0, 0, 0, 0);
                accO1 = __builtin_amdgcn_mfma_f32_32x32x16_bf16(v1, pf, accO1, 0, 0, 0);
            }
        }
    }
    const float L = lsum + __shfl_xor(lsum, 32);
    attn_epilogue(accO0, accO1, 1.0f / L, Wp, bp, vb, out + bofs,
                  q0 + l31, l31, hi);
}

extern "C" void kernel_launch(void* const* d_in, const int* in_sizes, int n_in,
                              void* d_out, int out_size, void* d_ws, size_t ws_size,
                              hipStream_t stream)
{
    const float* x  = (const float*)d_in[0];
    const float* Wq = (const float*)d_in[1];
    const float* Wp = (const float*)d_in[2];
    const float* bp = (const float*)d_in[3];
    float* out = (float*)d_out;

    unsigned short* qbuf = (unsigned short*)d_ws;                 // 3x 8*3136*64 bf16
    unsigned short* kbuf = qbuf + (size_t)8 * NTOK * 64;
    unsigned short* vTb  = kbuf + (size_t)8 * NTOK * 64;
    const size_t bf_bytes = (size_t)3 * 8 * NTOK * 64 * 2;        // 9.63 MB
    char* part = (char*)d_ws + bf_bytes;
    const size_t part_bytes = (size_t)8 * NQT * NCHUNK * PARTB;   // 13.6 MB
    unsigned short* WbT = (unsigned short*)((char*)d_ws + bf_bytes + part_bytes);
    const size_t need = bf_bytes + part_bytes + 192 * 160 * 2;    // ~23 MB

    if (ws_size >= need) {
        prep_w_kernel<<<dim3(120), 256, 0, stream>>>(Wq, WbT);
        qkv_mfma_kernel<<<dim3(8 * NTOK / 32), 384, 0, stream>>>(x, WbT, qbuf, kbuf, vTb);
        attn_split_kernel<<<dim3(QTB8, 8, NCHUNK), 512, 0, stream>>>(qbuf, kbuf, vTb, part);
        attn_combine_kernel<<<dim3(8 * NQT / 4), 256, 0, stream>>>(part, vTb, Wp, bp, out);
    } else {
        prep_w_kernel<<<dim3(120), 256, 0, stream>>>(Wq, (unsigned short*)part);
        qkv_mfma_kernel<<<dim3(8 * NTOK / 32), 384, 0, stream>>>(x, (unsigned short*)part, qbuf, kbuf, vTb);
        attn_kernel<<<dim3(NQT, 8), 64, 0, stream>>>(qbuf, kbuf, vTb, Wp, bp, out);
    }
}

// Round 23
// 57.148 us; speedup vs baseline: 1.0297x; 1.0077x over previous
//
#include <hip/hip_runtime.h>

typedef short  bhalf8   __attribute__((ext_vector_type(8)));   // 8 bf16 (4 VGPRs)
typedef float  floatx16 __attribute__((ext_vector_type(16)));  // MFMA 32x32 acc
typedef float  float4e  __attribute__((ext_vector_type(4)));

#define NTOK 3136
#define CDIM 147
#define NQT  98    // 3136/32 q-tiles
#define KVT  49    // 3136/64 kv-tiles
#define NCHUNK 4
#define QTB8 13    // ceil(98/8) q-tile groups (8 waves/block)
#define PARTB 4352 // bytes per partial: 2 regions x 2048 (bf16 O) + 256 (fp32 l)

static __device__ __forceinline__ unsigned short f2bf(float f) {
    unsigned u = __float_as_uint(f);
    u += 0x7fffu + ((u >> 16) & 1u);            // round-to-nearest-even
    return (unsigned short)(u >> 16);
}
static __device__ __forceinline__ float bf2f(unsigned short h) {
    return __uint_as_float(((unsigned)h) << 16);
}
// packed f32x2 -> bf16x2 via HW cvt (T12 recipe; no builtin on gfx950)
static __device__ __forceinline__ unsigned packbf2(float a, float b) {
    unsigned r;
    asm("v_cvt_pk_bf16_f32 %0, %1, %2" : "=v"(r) : "v"(a), "v"(b));
    return r;
}
static __device__ __forceinline__ float fexp2(float x) {
#if __has_builtin(__builtin_amdgcn_exp2f)
    return __builtin_amdgcn_exp2f(x);
#else
    return __expf(x * 0.69314718056f);
#endif
}

// ---------------------------------------------------------------------------
// Kernel 0: WbT[c][k] = bf16(W[k][c]), K padded 147->160. 192x160.
// ---------------------------------------------------------------------------
__global__ __launch_bounds__(256) void prep_w_kernel(
    const float* __restrict__ W, unsigned short* __restrict__ WbT)
{
    const int idx = blockIdx.x * 256 + threadIdx.x;
    if (idx >= 192 * 160) return;
    const int c = idx / 160, k = idx - c * 160;
    WbT[idx] = (k < CDIM) ? f2bf(W[(size_t)k * 192 + c]) : (unsigned short)0;
}

// ---------------------------------------------------------------------------
// Kernel 1: qkv via MFMA (q pre-scaled by SM = 0.125*log2e).
// ---------------------------------------------------------------------------
__global__ __launch_bounds__(384) void qkv_mfma_kernel(
    const float* __restrict__ x, const unsigned short* __restrict__ WbT,
    unsigned short* __restrict__ qb, unsigned short* __restrict__ kb,
    unsigned short* __restrict__ vT)
{
    __shared__ __align__(16) unsigned char xls[32 * 384];
    const int tid = threadIdx.x;
    const int wave = tid >> 6, lane = tid & 63;
    const int l31 = lane & 31, hi = lane >> 5;
    const int n0g = blockIdx.x * 32;
    const int b = n0g / NTOK, nn0 = n0g - b * NTOK;
    const float SM = 0.125f * 1.44269504f;      // scale * log2(e)

    for (int i = tid; i < 640; i += 384) {
        const int row = i / 20, c = i - row * 20;
        const float* src = x + (size_t)(n0g + row) * CDIM + c * 8;
        float f[8];
        if (c < 18) {
            const float4e a = *reinterpret_cast<const float4e*>(src);
            const float4e v2 = *reinterpret_cast<const float4e*>(src + 4);
            f[0]=a[0]; f[1]=a[1]; f[2]=a[2]; f[3]=a[3];
            f[4]=v2[0]; f[5]=v2[1]; f[6]=v2[2]; f[7]=v2[3];
        } else if (c == 18) {
            f[0]=src[0]; f[1]=src[1]; f[2]=src[2];
            f[3]=f[4]=f[5]=f[6]=f[7]=0.f;
        } else {
            f[0]=f[1]=f[2]=f[3]=f[4]=f[5]=f[6]=f[7]=0.f;
        }
        uint4 u;
        u.x = packbf2(f[0], f[1]); u.y = packbf2(f[2], f[3]);
        u.z = packbf2(f[4], f[5]); u.w = packbf2(f[6], f[7]);
        const int phys = (c & ~7) | ((c & 7) ^ (row & 7));
        *reinterpret_cast<uint4*>(&xls[row * 384 + phys * 16]) = u;
    }
    __syncthreads();

    const int wcol = wave * 32;                 // W col tile (q|k|v contiguous)
    const bhalf8* wrow = reinterpret_cast<const bhalf8*>(WbT + (size_t)(wcol + l31) * 160);
    floatx16 acc;
#pragma unroll
    for (int r = 0; r < 16; ++r) acc[r] = 0.f;

    if (wave < 4) {
#pragma unroll
        for (int s = 0; s < 10; ++s) {
            const int slot = 2 * s + hi;
            const int phys = (slot & ~7) | ((slot & 7) ^ (l31 & 7));
            const bhalf8 xf = *reinterpret_cast<const bhalf8*>(&xls[l31 * 384 + phys * 16]);
            acc = __builtin_amdgcn_mfma_f32_32x32x16_bf16(xf, wrow[slot], acc, 0, 0, 0);
        }
        unsigned short* dst = (wave < 2) ? qb : kb;
        const float scl = (wave < 2) ? SM : 1.0f;   // fold softmax scale into q
        const int c0 = (wave & 1) * 32 + l31;
#pragma unroll
        for (int r = 0; r < 16; ++r) {
            const int n = n0g + (r & 3) + 8 * (r >> 2) + 4 * hi;
            dst[(size_t)n * 64 + c0] = f2bf(acc[r] * scl);
        }
    } else {
#pragma unroll
        for (int s = 0; s < 10; ++s) {
            const int slot = 2 * s + hi;
            const int phys = (slot & ~7) | ((slot & 7) ^ (l31 & 7));
            const bhalf8 xf = *reinterpret_cast<const bhalf8*>(&xls[l31 * 384 + phys * 16]);
            acc = __builtin_amdgcn_mfma_f32_32x32x16_bf16(wrow[slot], xf, acc, 0, 0, 0);
        }
        const int nc = nn0 + l31;
#pragma unroll
        for (int r = 0; r < 16; ++r) {
            const int c = (wave - 4) * 32 + (r & 3) + 8 * (r >> 2) + 4 * hi;
            vT[((size_t)b * 64 + c) * NTOK + nc] = f2bf(acc[r]);
        }
    }
}

// ---------------------------------------------------------------------------
// Fragment builder (cvt_pk + lane32-swap expressed portably; round-0 note)
// ---------------------------------------------------------------------------
static __device__ __forceinline__ bhalf8 build_frag(unsigned a0, unsigned a1,
                                                    unsigned a2, unsigned a3, int hi)
{
    const unsigned py1 = __shfl_xor(hi ? a0 : a2, 32);
    const unsigned py2 = __shfl_xor(hi ? a1 : a3, 32);
    union { unsigned w[4]; bhalf8 v; } f;
    f.w[0] = hi ? py1 : a0;
    f.w[1] = hi ? py2 : a1;
    f.w[2] = hi ? a2 : py1;
    f.w[3] = hi ? a3 : py2;
    return f.v;
}

// Shared epilogue: out^T = W^T.(O/l) then +b +v, scattered fp32 stores
static __device__ __forceinline__ void attn_epilogue(
    const floatx16& accO0, const floatx16& accO1, float inv,
    const float* __restrict__ Wp, const float* __restrict__ bp,
    const unsigned short* __restrict__ vb, float* __restrict__ orow,
    int q, int l31, int hi)
{
    unsigned ok0[8], ok1[8];
#pragma unroll
    for (int w = 0; w < 8; ++w) {
        ok0[w] = packbf2(accO0[2 * w] * inv, accO0[2 * w + 1] * inv);
        ok1[w] = packbf2(accO1[2 * w] * inv, accO1[2 * w + 1] * inv);
    }
    floatx16 accP0, accP1;
#pragma unroll
    for (int r = 0; r < 16; ++r) { accP0[r] = 0.f; accP1[r] = 0.f; }
#pragma unroll
    for (int ks = 0; ks < 4; ++ks) {
        const int t = ks & 1;
        const bhalf8 of = (ks >> 1) ? build_frag(ok1[4*t], ok1[4*t+1], ok1[4*t+2], ok1[4*t+3], hi)
                                    : build_frag(ok0[4*t], ok0[4*t+1], ok0[4*t+2], ok0[4*t+3], hi);
        union { unsigned w[4]; bhalf8 v; } wa, wb;
#pragma unroll
        for (int jj = 0; jj < 4; ++jj) {
            const int d0 = 16 * ks + 8 * hi + 2 * jj;
            wa.w[jj] = packbf2(Wp[(size_t)d0 * 64 + l31],      Wp[(size_t)(d0 + 1) * 64 + l31]);
            wb.w[jj] = packbf2(Wp[(size_t)d0 * 64 + 32 + l31], Wp[(size_t)(d0 + 1) * 64 + 32 + l31]);
        }
        accP0 = __builtin_amdgcn_mfma_f32_32x32x16_bf16(wa.v, of, accP0, 0, 0, 0);
        accP1 = __builtin_amdgcn_mfma_f32_32x32x16_bf16(wb.v, of, accP1, 0, 0, 0);
    }
#pragma unroll
    for (int r = 0; r < 16; ++r) {
        const int e0 = (r & 3) + 8 * (r >> 2) + 4 * hi;
        const int e1 = e0 + 32;
        const float va = bf2f(vb[(size_t)e0 * NTOK + q]);
        const float vc = bf2f(vb[(size_t)e1 * NTOK + q]);
        orow[(size_t)q * 64 + e0] = accP0[r] + bp[e0] + va;
        orow[(size_t)q * 64 + e1] = accP1[r] + bp[e1] + vc;
    }
}

// ---------------------------------------------------------------------------
// Kernel 2a: LDS-staged split-K flash attention (no-max), bf16 partials.
// Best-known config: 8 waves / 8 q-tiles share one K/V stage, 32KB
// double-buffer, 1 barrier/tile, plain stores, NCHUNK=4, separate combine.
// ---------------------------------------------------------------------------
__global__ __launch_bounds__(512) void attn_split_kernel(
    const unsigned short* __restrict__ qb,
    const unsigned short* __restrict__ kbf,
    const unsigned short* __restrict__ vT,
    char* __restrict__ part)
{
    __shared__ __align__(16) unsigned char lds[2][16384];  // [buf][K 8KB | V 8KB]
    const int tid  = threadIdx.x;
    const int wave = tid >> 6, lane = tid & 63;
    const int l31 = lane & 31, hi = lane >> 5;
    const int qtb = blockIdx.x, b = blockIdx.y, ck = blockIdx.z;
    int qt = qtb * 8 + wave; if (qt >= NQT) qt = NQT - 1;   // dup work, benign
    const size_t bofs = (size_t)b * NTOK * 64;
    const int q0 = qt * 32;

    const bhalf8* qrow = reinterpret_cast<const bhalf8*>(qb + bofs + (size_t)(q0 + l31) * 64);
    bhalf8 Qf[4];
#pragma unroll
    for (int s = 0; s < 4; ++s) Qf[s] = qrow[2 * s + hi];

    floatx16 accO0, accO1, z16;
#pragma unroll
    for (int r = 0; r < 16; ++r) { accO0[r] = 0.f; accO1[r] = 0.f; z16[r] = 0.f; }
    float lsum = 0.f;

    const unsigned short* vb = vT + (size_t)b * 64 * NTOK;
    const int kv_lo = (ck * KVT) / NCHUNK;
    const int kv_hi = ((ck + 1) * KVT) / NCHUNK;

    // staging: 512 threads cover the 512 16B slots of K and of V
    const int r0 = tid >> 3,  s0i = tid & 7;       // row 0..63, slot 0..7
    const int swz0 = (s0i ^ (r0 & 7)) << 4;
    uint4 rK, rV;

#define STAGE_LOAD(kvt_) do {                                                   \
        rK = reinterpret_cast<const uint4*>(                                    \
            kbf + bofs + (size_t)(kvt_) * 64 * 64)[tid];                        \
        rV = *reinterpret_cast<const uint4*>(                                   \
            vb + (size_t)r0 * NTOK + (kvt_) * 64 + s0i * 8);                    \
    } while (0)

#define STAGE_WRITE(buf_) do {                                                  \
        *reinterpret_cast<uint4*>(&lds[buf_][r0 * 128 + swz0])        = rK;     \
        *reinterpret_cast<uint4*>(&lds[buf_][8192 + r0 * 128 + swz0]) = rV;     \
    } while (0)

    STAGE_LOAD(kv_lo);
    int buf = 0;
    const int kswz = (l31 & 7);
    for (int kvt = kv_lo; kvt < kv_hi; ++kvt) {
        STAGE_WRITE(buf);
        if (kvt + 1 < kv_hi) STAGE_LOAD(kvt + 1);  // prefetch under compute
        __syncthreads();

        // ---- QK^T from LDS (first k-step consumes persistent z16) ----
        floatx16 s0, s1;
        {
            const int sl = (hi ^ kswz) << 4;
            const bhalf8 kf0 = *reinterpret_cast<const bhalf8*>(&lds[buf][l31 * 128 + sl]);
            const bhalf8 kf1 = *reinterpret_cast<const bhalf8*>(&lds[buf][(32 + l31) * 128 + sl]);
            s0 = __builtin_amdgcn_mfma_f32_32x32x16_bf16(kf0, Qf[0], z16, 0, 0, 0);
            s1 = __builtin_amdgcn_mfma_f32_32x32x16_bf16(kf1, Qf[0], z16, 0, 0, 0);
        }
#pragma unroll
        for (int s = 1; s < 4; ++s) {
            const int sl = ((2 * s + hi) ^ kswz) << 4;
            const bhalf8 kf0 = *reinterpret_cast<const bhalf8*>(&lds[buf][l31 * 128 + sl]);
            const bhalf8 kf1 = *reinterpret_cast<const bhalf8*>(&lds[buf][(32 + l31) * 128 + sl]);
            s0 = __builtin_amdgcn_mfma_f32_32x32x16_bf16(kf0, Qf[s], s0, 0, 0, 0);
            s1 = __builtin_amdgcn_mfma_f32_32x32x16_bf16(kf1, Qf[s], s1, 0, 0, 0);
        }
        // ---- no-max softmax (scale pre-folded into q) ----
        float ps0 = 0.f, ps1 = 0.f;
#pragma unroll
        for (int r = 0; r < 16; ++r) {
            const float p0 = fexp2(s0[r]); s0[r] = p0;
            const float p1 = fexp2(s1[r]); s1[r] = p1;
            ps0 += p0; ps1 += p1;
        }
        lsum += ps0 + ps1;
        unsigned pk0[8], pk1[8];
#pragma unroll
        for (int w = 0; w < 8; ++w) {
            pk0[w] = packbf2(s0[2 * w], s0[2 * w + 1]);
            pk1[w] = packbf2(s1[2 * w], s1[2 * w + 1]);
        }
        // ---- PV from LDS ----
#pragma unroll
        for (int u = 0; u < 2; ++u) {
#pragma unroll
            for (int t = 0; t < 2; ++t) {
                const bhalf8 pf = u ? build_frag(pk1[4*t], pk1[4*t+1], pk1[4*t+2], pk1[4*t+3], hi)
                                    : build_frag(pk0[4*t], pk0[4*t+1], pk0[4*t+2], pk0[4*t+3], hi);
                const int sl = ((4 * u + 2 * t + hi) ^ kswz) << 4;
                const bhalf8 v0 = *reinterpret_cast<const bhalf8*>(&lds[buf][8192 + l31 * 128 + sl]);
                const bhalf8 v1 = *reinterpret_cast<const bhalf8*>(&lds[buf][8192 + (32 + l31) * 128 + sl]);
                accO0 = __builtin_amdgcn_mfma_f32_32x32x16_bf16(v0, pf, accO0, 0, 0, 0);
                accO1 = __builtin_amdgcn_mfma_f32_32x32x16_bf16(v1, pf, accO1, 0, 0, 0);
            }
        }
        buf ^= 1;
    }
#undef STAGE_LOAD
#undef STAGE_WRITE

    char* pbb = part + ((size_t)(b * NQT + qt) * NCHUNK + ck) * PARTB;
#pragma unroll
    for (int rg = 0; rg < 4; ++rg) {
        uint2 w0, w1;
        w0.x = packbf2(accO0[4*rg],     accO0[4*rg + 1]);
        w0.y = packbf2(accO0[4*rg + 2], accO0[4*rg + 3]);
        w1.x = packbf2(accO1[4*rg],     accO1[4*rg + 1]);
        w1.y = packbf2(accO1[4*rg + 2], accO1[4*rg + 3]);
        *reinterpret_cast<uint2*>(pbb + (rg * 64 + lane) * 8)        = w0;
        *reinterpret_cast<uint2*>(pbb + 2048 + (rg * 64 + lane) * 8) = w1;
    }
    *reinterpret_cast<float*>(pbb + 4096 + lane * 4) = lsum;
}

// ---------------------------------------------------------------------------
// Kernel 2b: combine bf16 partials (plain sum) + out-proj + bias + v.
// ---------------------------------------------------------------------------
__global__ __launch_bounds__(256) void attn_combine_kernel(
    const char* __restrict__ part,
    const unsigned short* __restrict__ vT,
    const float* __restrict__ Wp, const float* __restrict__ bp,
    float* __restrict__ out)
{
    const int wid  = blockIdx.x * 4 + (threadIdx.x >> 6);
    const int lane = threadIdx.x & 63;
    const int qt   = wid % NQT;
    const int b    = wid / NQT;
    const int l31 = lane & 31, hi = lane >> 5;
    const char* pbase = part + (size_t)(b * NQT + qt) * NCHUNK * PARTB;

    floatx16 accO0, accO1;
#pragma unroll
    for (int r = 0; r < 16; ++r) { accO0[r] = 0.f; accO1[r] = 0.f; }
    float lsum = 0.f;
#pragma unroll
    for (int c = 0; c < NCHUNK; ++c) {
        const char* pbb = pbase + (size_t)c * PARTB;
#pragma unroll
        for (int rg = 0; rg < 4; ++rg) {
            const uint2 u0 = *reinterpret_cast<const uint2*>(pbb + (rg * 64 + lane) * 8);
            const uint2 u1 = *reinterpret_cast<const uint2*>(pbb + 2048 + (rg * 64 + lane) * 8);
            accO0[4*rg]     += __uint_as_float(u0.x << 16);
            accO0[4*rg + 1] += __uint_as_float(u0.x & 0xffff0000u);
            accO0[4*rg + 2] += __uint_as_float(u0.y << 16);
            accO0[4*rg + 3] += __uint_as_float(u0.y & 0xffff0000u);
            accO1[4*rg]     += __uint_as_float(u1.x << 16);
            accO1[4*rg + 1] += __uint_as_float(u1.x & 0xffff0000u);
            accO1[4*rg + 2] += __uint_as_float(u1.y << 16);
            accO1[4*rg + 3] += __uint_as_float(u1.y & 0xffff0000u);
        }
        lsum += *reinterpret_cast<const float*>(pbb + 4096 + lane * 4);
    }
    const float L = lsum + __shfl_xor(lsum, 32);
    const unsigned short* vb = vT + (size_t)b * 64 * NTOK;
    attn_epilogue(accO0, accO1, 1.0f / L, Wp, bp, vb, out + (size_t)b * NTOK * 64,
                  qt * 32 + l31, l31, hi);
}

// ---------------------------------------------------------------------------
// Fallback: monolithic attention, global K/V reads (only if ws too small)
// ---------------------------------------------------------------------------
__global__ __launch_bounds__(64) void attn_kernel(
    const unsigned short* __restrict__ qb,
    const unsigned short* __restrict__ kbf,
    const unsigned short* __restrict__ vT,
    const float* __restrict__ Wp, const float* __restrict__ bp,
    float* __restrict__ out)
{
    const int qt = blockIdx.x, b = blockIdx.y;
    const int lane = threadIdx.x;
    const int l31 = lane & 31, hi = lane >> 5;
    const size_t bofs = (size_t)b * NTOK * 64;
    const int q0 = qt * 32;

    const bhalf8* qrow = reinterpret_cast<const bhalf8*>(qb + bofs + (size_t)(q0 + l31) * 64);
    bhalf8 Qf[4];
#pragma unroll
    for (int s = 0; s < 4; ++s) Qf[s] = qrow[2 * s + hi];

    floatx16 accO0, accO1;
#pragma unroll
    for (int r = 0; r < 16; ++r) { accO0[r] = 0.f; accO1[r] = 0.f; }
    float lsum = 0.f;
    const unsigned short* vb = vT + (size_t)b * 64 * NTOK;
    for (int kvt = 0; kvt < KVT; ++kvt) {
        const int kv0 = kvt * 64;
        const bhalf8* kr0 = reinterpret_cast<const bhalf8*>(kbf + bofs + (size_t)(kv0 + l31) * 64);
        const bhalf8* kr1 = reinterpret_cast<const bhalf8*>(kbf + bofs + (size_t)(kv0 + 32 + l31) * 64);
        floatx16 s0, s1;
#pragma unroll
        for (int r = 0; r < 16; ++r) { s0[r] = 0.f; s1[r] = 0.f; }
#pragma unroll
        for (int s = 0; s < 4; ++s) {
            s0 = __builtin_amdgcn_mfma_f32_32x32x16_bf16(kr0[2 * s + hi], Qf[s], s0, 0, 0, 0);
            s1 = __builtin_amdgcn_mfma_f32_32x32x16_bf16(kr1[2 * s + hi], Qf[s], s1, 0, 0, 0);
        }
        float ps0 = 0.f, ps1 = 0.f;
#pragma unroll
        for (int r = 0; r < 16; ++r) {
            const float p0 = fexp2(s0[r]); s0[r] = p0;
            const float p1 = fexp2(s1[r]); s1[r] = p1;
            ps0 += p0; ps1 += p1;
        }
        lsum += ps0 + ps1;
        unsigned pk0[8], pk1[8];
#pragma unroll
        for (int w = 0; w < 8; ++w) {
            pk0[w] = packbf2(s0[2 * w], s0[2 * w + 1]);
            pk1[w] = packbf2(s1[2 * w], s1[2 * w + 1]);
        }
#pragma unroll
        for (int u = 0; u < 2; ++u) {
#pragma unroll
            for (int t = 0; t < 2; ++t) {
                const bhalf8 pf = u ? build_frag(pk1[4*t], pk1[4*t+1], pk1[4*t+2], pk1[4*t+3], hi)
                                    : build_frag(pk0[4*t], pk0[4*t+1], pk0[4*t+2], pk0[4*t+3], hi);
                const int col = kv0 + 32 * u + 16 * t + 8 * hi;
                const bhalf8 v0 = *reinterpret_cast<const bhalf8*>(vb + (size_t)l31 * NTOK + col);
                const bhalf8 v1 = *reinterpret_cast<const bhalf8*>(vb + (size_t)(32 + l31) * NTOK + col);
                accO0 = __builtin_amdgcn_mfma_f32_32x32x16_bf16(v0, pf, accO0, 0, 0, 0);
                accO1 = __builtin_amdgcn_mfma_f32_32x32x16_bf16(v1, pf, accO1, 0, 0, 0);
            }
        }
    }
    const float L = lsum + __shfl_xor(lsum, 32);
    attn_epilogue(accO0, accO1, 1.0f / L, Wp, bp, vb, out + bofs,
                  q0 + l31, l31, hi);
}

extern "C" void kernel_launch(void* const* d_in, const int* in_sizes, int n_in,
                              void* d_out, int out_size, void* d_ws, size_t ws_size,
                              hipStream_t stream)
{
    const float* x  = (const float*)d_in[0];
    const float* Wq = (const float*)d_in[1];
    const float* Wp = (const float*)d_in[2];
    const float* bp = (const float*)d_in[3];
    float* out = (float*)d_out;

    unsigned short* qbuf = (unsigned short*)d_ws;                 // 3x 8*3136*64 bf16
    unsigned short* kbuf = qbuf + (size_t)8 * NTOK * 64;
    unsigned short* vTb  = kbuf + (size_t)8 * NTOK * 64;
    const size_t bf_bytes = (size_t)3 * 8 * NTOK * 64 * 2;        // 9.63 MB
    char* part = (char*)d_ws + bf_bytes;
    const size_t part_bytes = (size_t)8 * NQT * NCHUNK * PARTB;   // 13.6 MB
    unsigned short* WbT = (unsigned short*)((char*)d_ws + bf_bytes + part_bytes);
    const size_t need = bf_bytes + part_bytes + 192 * 160 * 2;    // ~23 MB

    if (ws_size >= need) {
        prep_w_kernel<<<dim3(120), 256, 0, stream>>>(Wq, WbT);
        qkv_mfma_kernel<<<dim3(8 * NTOK / 32), 384, 0, stream>>>(x, WbT, qbuf, kbuf, vTb);
        attn_split_kernel<<<dim3(QTB8, 8, NCHUNK), 512, 0, stream>>>(qbuf, kbuf, vTb, part);
        attn_combine_kernel<<<dim3(8 * NQT / 4), 256, 0, stream>>>(part, vTb, Wp, bp, out);
    } else {
        prep_w_kernel<<<dim3(120), 256, 0, stream>>>(Wq, (unsigned short*)part);
        qkv_mfma_kernel<<<dim3(8 * NTOK / 32), 384, 0, stream>>>(x, (unsigned short*)part, qbuf, kbuf, vTb);
        attn_kernel<<<dim3(NQT, 8), 64, 0, stream>>>(qbuf, kbuf, vTb, Wp, bp, out);
    }
}